// Round 9
// baseline (156.947 us; speedup 1.0000x reference)
//
#include <hip/hip_runtime.h>

// Fisher-Kolmogorov PDE: out = div(D * grad(u)) + rho * u * (1 - u)
// Per-axis reference semantics (replicate padding on u, then on flux):
//   div[c] = 0.25 * (f(min(c+1,n-1)) - f(max(c-1,0))),
//   f(j)   = D[j] * (u[min(j+1,n-1)] - u[max(j-1,0)])
// Shape: [B=4, C=1, 192^3], float32.
//
// R7 schedule (register-past / LDS-future, ONE barrier per plane) reworked for
// 4 voxels/thread: block (16,16)=256, tile 64x16, ZC=24. LROW=72 with center
// at col 4 makes ALL stencil LDS reads 16B-aligned ds_read_b128:
//   per thread-step: 13 b128 reads (vs 28 b64), ~6 float2 staging loads +
//   1 b128 rho (vs ~15 scalar), 1 b128 store.
// Rings: u {z,z+1,z+2,free} 4 slabs [20][72]; D {z,z+1,free} 3 slabs [18][72]
// (D needs y+-1 only) = 38.6 KB -> 4 blocks/CU.
// Edge staging pairs (gx0<0 or >190; gx0 always even) both clamp to the same
// index -> single scalar broadcast, no straddle case.

#define NX    192
#define SP    (NX * NX)
#define ZC    24
#define LROW  72
#define UROWS 20
#define DROWS 18
#define USLAB (UROWS * LROW)      // 1440 floats
#define DSLAB (DROWS * LROW)      // 1296 floats
#define NTHR  256
#define UPAIRS (USLAB / 2)        // 720
#define DPAIRS (DSLAB / 2)        // 648

#define LD4(p, o) (*(const float4*)((p) + (o)))

__global__ __launch_bounds__(NTHR, 4)
void fk_kernel(const float* __restrict__ u,
               const float* __restrict__ Dd,
               const float* __restrict__ rho,
               float* __restrict__ out)
{
    __shared__ float Ush[4 * USLAB];
    __shared__ float Dsh[3 * DSLAB];

    const int tx  = threadIdx.x;          // 0..15 -> 4 voxels at x0+4*tx
    const int ty  = threadIdx.y;          // 0..15
    const int tid = ty * 16 + tx;

    int bid = blockIdx.x;
    const int xt = bid % 3;  bid /= 3;
    const int yt = bid % 12; bid /= 12;
    const int zc = bid % 8;  bid /= 8;
    const int b  = bid;                   // 0..3

    const int x0 = xt * 64, y0 = yt * 16, z0 = zc * ZC;

    const size_t vol = (size_t)b * NX * SP;
    const float* ub = u   + vol;
    const float* db = Dd  + vol;
    const float* rb = rho + vol;
    float*       ob = out + vol;

    // ---- staging descriptors: float2 pairs; slab col c <-> gx = x0 + c - 4;
    //      u rows r <-> gy = y0+r-2 (20), D rows r <-> gy = y0+r-1 (18).
    int  uoff[3], doff[3];
    bool uedge[3], dedge[3];
    bool uact[3], dact[3];
    #pragma unroll
    for (int k = 0; k < 3; ++k) {
        {
            const int p = tid + NTHR * k;
            uact[k] = (p < UPAIRS);
            const int pp = uact[k] ? p : 0;
            const int r = pp / (LROW / 2), pc = pp % (LROW / 2);
            int gy = y0 + r - 2; gy = gy < 0 ? 0 : (gy > NX - 1 ? NX - 1 : gy);
            const int gx0 = x0 + 2 * pc - 4;
            const bool e = (gx0 < 0) || (gx0 > NX - 2);
            const int gxc = (gx0 < 0) ? 0 : NX - 1;
            uoff[k]  = gy * NX + (e ? gxc : gx0);
            uedge[k] = e;
        }
        {
            const int p = tid + NTHR * k;
            dact[k] = (p < DPAIRS);
            const int pp = dact[k] ? p : 0;
            const int r = pp / (LROW / 2), pc = pp % (LROW / 2);
            int gy = y0 + r - 1; gy = gy < 0 ? 0 : (gy > NX - 1 ? NX - 1 : gy);
            const int gx0 = x0 + 2 * pc - 4;
            const bool e = (gx0 < 0) || (gx0 > NX - 2);
            const int gxc = (gx0 < 0) ? 0 : NX - 1;
            doff[k]  = gy * NX + (e ? gxc : gx0);
            dedge[k] = e;
        }
    }

    auto stageU = [&](const float* pl, float2* s) {
        #pragma unroll
        for (int k = 0; k < 3; ++k) if (uact[k]) {
            if (!uedge[k]) s[k] = *(const float2*)(pl + uoff[k]);
            else { const float f = pl[uoff[k]]; s[k] = make_float2(f, f); }
        }
    };
    auto stageD = [&](const float* pl, float2* s) {
        #pragma unroll
        for (int k = 0; k < 3; ++k) if (dact[k]) {
            if (!dedge[k]) s[k] = *(const float2*)(pl + doff[k]);
            else { const float f = pl[doff[k]]; s[k] = make_float2(f, f); }
        }
    };
    auto writeU = [&](float* slab, const float2* s) {
        #pragma unroll
        for (int k = 0; k < 3; ++k) if (uact[k])
            *(float2*)(slab + 2 * (tid + NTHR * k)) = s[k];
    };
    auto writeD = [&](float* slab, const float2* s) {
        #pragma unroll
        for (int k = 0; k < 3; ++k) if (dact[k])
            *(float2*)(slab + 2 * (tid + NTHR * k)) = s[k];
    };

    // ---- ring init: u slabs 0..2 = planes z0..z0+2, D slabs 0..1 = z0..z0+1
    {
        float2 s[3];
        #pragma unroll
        for (int sI = 0; sI < 3; ++sI) {
            stageU(ub + (size_t)(z0 + sI) * SP, s);
            writeU(Ush + sI * USLAB, s);
        }
        #pragma unroll
        for (int sI = 0; sI < 2; ++sI) {
            stageD(db + (size_t)(z0 + sI) * SP, s);
            writeD(Dsh + sI * DSLAB, s);
        }
    }

    const int x = x0 + 4 * tx, y = y0 + ty;
    const size_t gcen = (size_t)y * NX + x;

    // per-thread register z-history (center column, clamped at z0 edge)
    const int zm1 = (z0 - 1 > 0) ? z0 - 1 : 0;
    const int zm2 = (z0 - 2 > 0) ? z0 - 2 : 0;
    float4 um1  = LD4(ub, (size_t)zm1 * SP + gcen);
    float4 um2  = LD4(ub, (size_t)zm2 * SP + gcen);
    float4 dm1  = LD4(db, (size_t)zm1 * SP + gcen);
    float4 rcur = LD4(rb, (size_t)z0 * SP + gcen);

    const int ubl = (ty + 2) * LROW + (4 * tx + 4);   // u slab center, 16B-aligned
    const int dbl = (ty + 1) * LROW + (4 * tx + 4);   // D slab center

    const bool fx0 = (x == 0);            // element 0 is global x=0
    const bool fx3 = (x + 3 == NX - 1);   // element 3 is global x=191
    const bool fy0 = (y == 0);
    const bool fy1 = (y == NX - 1);

    __syncthreads();

    int su0 = 0, su1 = 1, su2 = 2, su3 = 3;   // planes z, z+1, z+2, free
    int sd0 = 0, sd1 = 1, sd2 = 2;            // planes z, z+1, free

    for (int iz = 0; iz < ZC; ++iz) {
        const int z  = z0 + iz;
        const bool pf = (iz + 1 < ZC);        // block-uniform

        // ---- issue staging loads (written to free slabs at step bottom) ----
        float2 uS[3], dS[3];
        float4 rnx;
        if (pf) {
            const int zu = (z + 3 > NX - 1) ? NX - 1 : z + 3;
            const int zd = (z + 2 > NX - 1) ? NX - 1 : z + 2;
            stageU(ub + (size_t)zu * SP, uS);
            stageD(db + (size_t)zd * SP, dS);
            rnx = LD4(rb, (size_t)(z + 1) * SP + gcen);
        }

        // ---- taps: 13 aligned b128 LDS reads ----
        const float* Uc = Ush + su0 * USLAB;
        const float* Dc = Dsh + sd0 * DSLAB;
        const float4 uxm4 = LD4(Uc, ubl - 4);
        const float4 ucc  = LD4(Uc, ubl);
        const float4 uxp4 = LD4(Uc, ubl + 4);
        const float4 dxm4 = LD4(Dc, dbl - 4);
        const float4 dcc  = LD4(Dc, dbl);
        const float4 dxp4 = LD4(Dc, dbl + 4);
        const float4 uym2 = LD4(Uc, ubl - 2 * LROW);
        const float4 uyp2 = LD4(Uc, ubl + 2 * LROW);
        const float4 dym  = LD4(Dc, dbl - LROW);
        const float4 dyp  = LD4(Dc, dbl + LROW);
        const float4 uzp2 = LD4(Ush + su2 * USLAB, ubl);
        const float4 dzp  = LD4(Dsh + sd1 * DSLAB, dbl);

        // ---- x axis: window w8 = u[x-2..x+5], d6 = D[x-1..x+4] ----
        const float w8[8] = {uxm4.z, uxm4.w, ucc.x, ucc.y, ucc.z, ucc.w, uxp4.x, uxp4.y};
        const float d6[6] = {dxm4.w, dcc.x, dcc.y, dcc.z, dcc.w, dxp4.x};
        float divx[4];
        #pragma unroll
        for (int i = 0; i < 4; ++i)
            divx[i] = d6[i + 2] * (w8[i + 4] - w8[i + 2]) - d6[i] * (w8[i + 2] - w8[i]);
        // clamped halo makes x=1..190 exact; fix only the outermost cells:
        if (fx0) divx[0] = d6[2] * (w8[4] - w8[2]) - d6[1] * (w8[3] - w8[2]);
        if (fx3) divx[3] = d6[4] * (w8[5] - w8[4]) - d6[3] * (w8[5] - w8[3]);

        // ---- y axis ----
        float4 divy;
        if (fy0) {
            const float4 uyp1 = LD4(Uc, ubl + LROW);
            divy.x = dyp.x * (uyp2.x - ucc.x) - dym.x * (uyp1.x - ucc.x);
            divy.y = dyp.y * (uyp2.y - ucc.y) - dym.y * (uyp1.y - ucc.y);
            divy.z = dyp.z * (uyp2.z - ucc.z) - dym.z * (uyp1.z - ucc.z);
            divy.w = dyp.w * (uyp2.w - ucc.w) - dym.w * (uyp1.w - ucc.w);
        } else if (fy1) {
            const float4 uym1 = LD4(Uc, ubl - LROW);
            divy.x = dyp.x * (ucc.x - uym1.x) - dym.x * (ucc.x - uym2.x);
            divy.y = dyp.y * (ucc.y - uym1.y) - dym.y * (ucc.y - uym2.y);
            divy.z = dyp.z * (ucc.z - uym1.z) - dym.z * (ucc.z - uym2.z);
            divy.w = dyp.w * (ucc.w - uym1.w) - dym.w * (ucc.w - uym2.w);
        } else {
            divy.x = dyp.x * (uyp2.x - ucc.x) - dym.x * (ucc.x - uym2.x);
            divy.y = dyp.y * (uyp2.y - ucc.y) - dym.y * (ucc.y - uym2.y);
            divy.z = dyp.z * (uyp2.z - ucc.z) - dym.z * (ucc.z - uym2.z);
            divy.w = dyp.w * (uyp2.w - ucc.w) - dym.w * (ucc.w - uym2.w);
        }

        // ---- z axis (block-uniform edge branches; past from registers) ----
        float4 divz;
        if (z == 0) {
            const float4 uzp1 = LD4(Ush + su1 * USLAB, ubl);
            divz.x = dzp.x * (uzp2.x - ucc.x) - dm1.x * (uzp1.x - ucc.x);
            divz.y = dzp.y * (uzp2.y - ucc.y) - dm1.y * (uzp1.y - ucc.y);
            divz.z = dzp.z * (uzp2.z - ucc.z) - dm1.z * (uzp1.z - ucc.z);
            divz.w = dzp.w * (uzp2.w - ucc.w) - dm1.w * (uzp1.w - ucc.w);
        } else if (z == NX - 1) {
            divz.x = dzp.x * (ucc.x - um1.x) - dm1.x * (ucc.x - um2.x);
            divz.y = dzp.y * (ucc.y - um1.y) - dm1.y * (ucc.y - um2.y);
            divz.z = dzp.z * (ucc.z - um1.z) - dm1.z * (ucc.z - um2.z);
            divz.w = dzp.w * (ucc.w - um1.w) - dm1.w * (ucc.w - um2.w);
        } else {
            divz.x = dzp.x * (uzp2.x - ucc.x) - dm1.x * (ucc.x - um2.x);
            divz.y = dzp.y * (uzp2.y - ucc.y) - dm1.y * (ucc.y - um2.y);
            divz.z = dzp.z * (uzp2.z - ucc.z) - dm1.z * (ucc.z - um2.z);
            divz.w = dzp.w * (uzp2.w - ucc.w) - dm1.w * (ucc.w - um2.w);
        }

        // ---- reaction + store ----
        float4 o;
        o.x = 0.25f * (divx[0] + divy.x + divz.x) + rcur.x * ucc.x * (1.0f - ucc.x);
        o.y = 0.25f * (divx[1] + divy.y + divz.y) + rcur.y * ucc.y * (1.0f - ucc.y);
        o.z = 0.25f * (divx[2] + divy.z + divz.z) + rcur.z * ucc.z * (1.0f - ucc.z);
        o.w = 0.25f * (divx[3] + divy.w + divz.w) + rcur.w * ucc.w * (1.0f - ucc.w);
        *(float4*)(ob + (size_t)z * SP + gcen) = o;

        // ---- roll register history ----
        um2 = um1; um1 = ucc; dm1 = dcc;

        // ---- write staged planes into FREE slabs, ONE barrier, rotate ----
        if (pf) {
            writeU(Ush + su3 * USLAB, uS);
            writeD(Dsh + sd2 * DSLAB, dS);
            __syncthreads();
            int t = su0; su0 = su1; su1 = su2; su2 = su3; su3 = t;
            t = sd0; sd0 = sd1; sd1 = sd2; sd2 = t;
            rcur = rnx;
        }
    }
}

extern "C" void kernel_launch(void* const* d_in, const int* in_sizes, int n_in,
                              void* d_out, int out_size, void* d_ws, size_t ws_size,
                              hipStream_t stream) {
    const float* u   = (const float*)d_in[0];
    const float* Dd  = (const float*)d_in[1];
    const float* rho = (const float*)d_in[2];
    float* out = (float*)d_out;

    dim3 block(16, 16, 1);                     // 256 threads, 4 voxels each
    const int grid = 3 * 12 * 8 * 4;           // xt*yt*zc*b = 1152
    fk_kernel<<<grid, block, 0, stream>>>(u, Dd, rho, out);
}

// Round 10
// 120.045 us; speedup vs baseline: 1.3074x; 1.3074x over previous
//
#include <hip/hip_runtime.h>

// Fisher-Kolmogorov PDE: out = div(D * grad(u)) + rho * u * (1 - u)
// Per-axis reference semantics (replicate padding on u, then on flux):
//   div[c] = 0.25 * (f(min(c+1,n-1)) - f(max(c-1,0))),
//   f(j)   = D[j] * (u[min(j+1,n-1)] - u[max(j-1,0)])
// Shape: [B=4, C=1, 192^3], float32.
//
// R7/R8 family (register-past / LDS-future, free-slab staging) with TWO
// z-planes per barrier: per double-step, stage u[z+4],u[z+5],D[z+3],D[z+4]
// into 2 free slabs each; compute planes z and z+1 back-to-back (plane B's
// z-past comes from plane A's just-read center values); ONE __syncthreads.
// 12 barriers/block instead of 24; 2x the independent work per latency chain.
// Rings: u {z..z+3, F1, F2} = 6 slabs, D {z..z+2, G1, G2} = 5 slabs,
// slab [20][68] floats; LDS = 58.4 KB -> 2 blocks/CU.

#define NX   192
#define SP   (NX * NX)
#define ZC   24
#define LROW 68
#define SROW 20
#define SLAB (SROW * LROW)            // 1360 floats
#define NTHR 512

#define LD2(p, o) (*(const float2*)((p) + (o)))

__global__ __launch_bounds__(NTHR, 4)
void fk_kernel(const float* __restrict__ u,
               const float* __restrict__ Dd,
               const float* __restrict__ rho,
               float* __restrict__ out)
{
    __shared__ float Ush[6 * SLAB];
    __shared__ float Dsh[5 * SLAB];

    const int tx  = threadIdx.x;              // 0..31
    const int ty  = threadIdx.y;              // 0..15
    const int tid = ty * 32 + tx;             // 0..511

    int bid = blockIdx.x;
    const int xt = bid % 3;  bid /= 3;
    const int yt = bid % 12; bid /= 12;
    const int zc = bid % 8;  bid /= 8;
    const int b  = bid;                       // 0..3

    const int x0 = xt * 64, y0 = yt * 16, z0 = zc * ZC;

    const size_t vol = (size_t)b * NX * SP;
    const float* ub = u   + vol;
    const float* db = Dd  + vol;
    const float* rb = rho + vol;
    float*       ob = out + vol;

    // staging map: slab flat position -> clamped global (y,x) plane offset
    int g0, g1, g2;
    {
        #pragma unroll
        for (int k = 0; k < 3; ++k) {
            const int p  = tid + NTHR * k;
            const int pp = (p < SLAB) ? p : 0;
            const int r = pp / LROW, c = pp % LROW;
            int gy = y0 + r - 2; gy = gy < 0 ? 0 : (gy > NX - 1 ? NX - 1 : gy);
            int gx = x0 + c - 2; gx = gx < 0 ? 0 : (gx > NX - 1 ? NX - 1 : gx);
            const int go = gy * NX + gx;
            if (k == 0) g0 = go; else if (k == 1) g1 = go; else g2 = go;
        }
    }
    const bool a2 = (tid < SLAB - 2 * NTHR);  // tid < 336

    // ---- ring init: u slabs 0..3 = planes z0..z0+3, D slabs 0..2 = z0..z0+2
    #pragma unroll
    for (int s = 0; s < 4; ++s) {
        const float* src = ub + (size_t)(z0 + s) * SP;
        Ush[s * SLAB + tid]        = src[g0];
        Ush[s * SLAB + tid + NTHR] = src[g1];
        if (a2) Ush[s * SLAB + tid + 2 * NTHR] = src[g2];
    }
    #pragma unroll
    for (int s = 0; s < 3; ++s) {
        const float* src = db + (size_t)(z0 + s) * SP;
        Dsh[s * SLAB + tid]        = src[g0];
        Dsh[s * SLAB + tid + NTHR] = src[g1];
        if (a2) Dsh[s * SLAB + tid + 2 * NTHR] = src[g2];
    }

    const int x  = x0 + 2 * tx;               // voxels x, x+1
    const int y  = y0 + ty;
    const int bl = (ty + 2) * LROW + (2 * tx + 2);
    const size_t gcen = (size_t)y * NX + x;

    const bool fx0 = (x == 0);
    const bool fx1 = (x + 1 == NX - 1);
    const bool fy0 = (y == 0);
    const bool fy1 = (y == NX - 1);

    // per-thread register z-history (center column, clamped at z0 edge)
    const int zm1 = (z0 - 1 > 0) ? z0 - 1 : 0;
    const int zm2 = (z0 - 2 > 0) ? z0 - 2 : 0;
    float2 um1 = *(const float2*)(ub + (size_t)zm1 * SP + gcen);
    float2 um2 = *(const float2*)(ub + (size_t)zm2 * SP + gcen);
    float2 dm1 = *(const float2*)(db + (size_t)zm1 * SP + gcen);
    float2 rA  = *(const float2*)(rb + (size_t)z0 * SP + gcen);
    float2 rB  = *(const float2*)(rb + (size_t)(z0 + 1) * SP + gcen);

    __syncthreads();

    int su0 = 0, su1 = 1, su2 = 2, su3 = 3, su4 = 4, su5 = 5;  // z..z+3, F1, F2
    int sd0 = 0, sd1 = 1, sd2 = 2, sd3 = 3, sd4 = 4;           // z..z+2, G1, G2

    for (int iz = 0; iz < ZC; iz += 2) {
        const int z  = z0 + iz;
        const bool pf = (iz + 2 < ZC);        // block-uniform

        // ---- issue staging loads for 2 planes (written at step bottom) ----
        float sua0, sua1, sua2, sub0, sub1, sub2;
        float sda0, sda1, sda2, sdb0, sdb1, sdb2;
        float2 rnA, rnB;
        if (pf) {
            const int zu1 = (z + 4 > NX - 1) ? NX - 1 : z + 4;
            const int zu2 = (z + 5 > NX - 1) ? NX - 1 : z + 5;
            const int zd1 = (z + 3 > NX - 1) ? NX - 1 : z + 3;
            const int zd2 = (z + 4 > NX - 1) ? NX - 1 : z + 4;
            const float* usA = ub + (size_t)zu1 * SP;
            const float* usB = ub + (size_t)zu2 * SP;
            const float* dsA = db + (size_t)zd1 * SP;
            const float* dsB = db + (size_t)zd2 * SP;
            sua0 = usA[g0]; sua1 = usA[g1]; if (a2) sua2 = usA[g2];
            sub0 = usB[g0]; sub1 = usB[g1]; if (a2) sub2 = usB[g2];
            sda0 = dsA[g0]; sda1 = dsA[g1]; if (a2) sda2 = dsA[g2];
            sdb0 = dsB[g0]; sdb1 = dsB[g1]; if (a2) sdb2 = dsB[g2];
            rnA = *(const float2*)(rb + (size_t)(z + 2) * SP + gcen);
            rnB = *(const float2*)(rb + (size_t)(z + 3) * SP + gcen);
        }

        // ================= plane A (z) =================
        const float* UcA = Ush + su0 * SLAB;
        const float* DcA = Dsh + sd0 * SLAB;
        const float2 uccA = LD2(UcA, bl);
        const float2 uxmA = LD2(UcA, bl - 2);
        const float2 uxpA = LD2(UcA, bl + 2);
        const float2 uymA = LD2(UcA, bl - 2 * LROW);
        const float2 uypA = LD2(UcA, bl + 2 * LROW);
        const float2 dccA = LD2(DcA, bl);
        const float2 dxmA = LD2(DcA, bl - 2);
        const float2 dxpA = LD2(DcA, bl + 2);
        const float2 dymA = LD2(DcA, bl - LROW);
        const float2 dypA = LD2(DcA, bl + LROW);
        const float2 uzp2A = LD2(Ush + su2 * SLAB, bl);   // u[z+2]
        const float2 dzpA  = LD2(Dsh + sd1 * SLAB, bl);   // D[z+1]

        float divx_xA = dccA.y * (uxpA.x - uccA.x) - dxmA.y * (uccA.x - uxmA.x);
        float divx_yA = dxpA.x * (uxpA.y - uccA.y) - dccA.x * (uccA.y - uxmA.y);
        if (fx0) divx_xA = dccA.y * (uxpA.x - uccA.x) - dccA.x * (uccA.y - uccA.x);
        if (fx1) divx_yA = dccA.y * (uccA.y - uccA.x) - dccA.x * (uccA.y - uxmA.y);

        float divy_xA = dypA.x * (uypA.x - uccA.x) - dymA.x * (uccA.x - uymA.x);
        float divy_yA = dypA.y * (uypA.y - uccA.y) - dymA.y * (uccA.y - uymA.y);
        if (fy0) {
            const float2 uyp1 = LD2(UcA, bl + LROW);
            divy_xA = dypA.x * (uypA.x - uccA.x) - dymA.x * (uyp1.x - uccA.x);
            divy_yA = dypA.y * (uypA.y - uccA.y) - dymA.y * (uyp1.y - uccA.y);
        }
        if (fy1) {
            const float2 uym1 = LD2(UcA, bl - LROW);
            divy_xA = dypA.x * (uccA.x - uym1.x) - dymA.x * (uccA.x - uymA.x);
            divy_yA = dypA.y * (uccA.y - uym1.y) - dymA.y * (uccA.y - uymA.y);
        }

        float divz_xA = dzpA.x * (uzp2A.x - uccA.x) - dm1.x * (uccA.x - um2.x);
        float divz_yA = dzpA.y * (uzp2A.y - uccA.y) - dm1.y * (uccA.y - um2.y);
        if (z == 0) {                          // plane A can be z==0 only
            const float2 uzp1 = LD2(Ush + su1 * SLAB, bl);
            divz_xA = dzpA.x * (uzp2A.x - uccA.x) - dm1.x * (uzp1.x - uccA.x);
            divz_yA = dzpA.y * (uzp2A.y - uccA.y) - dm1.y * (uzp1.y - uccA.y);
        }

        float2 oA;
        oA.x = 0.25f * (divx_xA + divy_xA + divz_xA) + rA.x * uccA.x * (1.0f - uccA.x);
        oA.y = 0.25f * (divx_yA + divy_yA + divz_yA) + rA.y * uccA.y * (1.0f - uccA.y);
        *(float2*)(ob + (size_t)z * SP + gcen) = oA;

        // ================= plane B (z+1) =================
        const float* UcB = Ush + su1 * SLAB;
        const float* DcB = Dsh + sd1 * SLAB;
        const float2 uccB = LD2(UcB, bl);
        const float2 uxmB = LD2(UcB, bl - 2);
        const float2 uxpB = LD2(UcB, bl + 2);
        const float2 uymB = LD2(UcB, bl - 2 * LROW);
        const float2 uypB = LD2(UcB, bl + 2 * LROW);
        const float2 dccB = LD2(DcB, bl);
        const float2 dxmB = LD2(DcB, bl - 2);
        const float2 dxpB = LD2(DcB, bl + 2);
        const float2 dymB = LD2(DcB, bl - LROW);
        const float2 dypB = LD2(DcB, bl + LROW);
        const float2 uzp2B = LD2(Ush + su3 * SLAB, bl);   // u[z+3]
        const float2 dzpB  = LD2(Dsh + sd2 * SLAB, bl);   // D[z+2]

        float divx_xB = dccB.y * (uxpB.x - uccB.x) - dxmB.y * (uccB.x - uxmB.x);
        float divx_yB = dxpB.x * (uxpB.y - uccB.y) - dccB.x * (uccB.y - uxmB.y);
        if (fx0) divx_xB = dccB.y * (uxpB.x - uccB.x) - dccB.x * (uccB.y - uccB.x);
        if (fx1) divx_yB = dccB.y * (uccB.y - uccB.x) - dccB.x * (uccB.y - uxmB.y);

        float divy_xB = dypB.x * (uypB.x - uccB.x) - dymB.x * (uccB.x - uymB.x);
        float divy_yB = dypB.y * (uypB.y - uccB.y) - dymB.y * (uccB.y - uymB.y);
        if (fy0) {
            const float2 uyp1 = LD2(UcB, bl + LROW);
            divy_xB = dypB.x * (uypB.x - uccB.x) - dymB.x * (uyp1.x - uccB.x);
            divy_yB = dypB.y * (uypB.y - uccB.y) - dymB.y * (uyp1.y - uccB.y);
        }
        if (fy1) {
            const float2 uym1 = LD2(UcB, bl - LROW);
            divy_xB = dypB.x * (uccB.x - uym1.x) - dymB.x * (uccB.x - uymB.x);
            divy_yB = dypB.y * (uccB.y - uym1.y) - dymB.y * (uccB.y - uymB.y);
        }

        // plane B z-past: u[z] = uccA, u[z-1] = um1, D[z] = dccA
        float divz_xB = dzpB.x * (uzp2B.x - uccB.x) - dccA.x * (uccB.x - um1.x);
        float divz_yB = dzpB.y * (uzp2B.y - uccB.y) - dccA.y * (uccB.y - um1.y);
        if (z + 1 == NX - 1) {                 // plane B can be z==191 only
            divz_xB = dzpB.x * (uccB.x - uccA.x) - dccA.x * (uccB.x - um1.x);
            divz_yB = dzpB.y * (uccB.y - uccA.y) - dccA.y * (uccB.y - um1.y);
        }

        float2 oB;
        oB.x = 0.25f * (divx_xB + divy_xB + divz_xB) + rB.x * uccB.x * (1.0f - uccB.x);
        oB.y = 0.25f * (divx_yB + divy_yB + divz_yB) + rB.y * uccB.y * (1.0f - uccB.y);
        *(float2*)(ob + (size_t)(z + 1) * SP + gcen) = oB;

        // ---- roll register history to plane z+2's viewpoint ----
        um2 = uccA; um1 = uccB; dm1 = dccB;

        // ---- write staged planes into free slabs, ONE barrier, rotate ----
        if (pf) {
            float* Uw1 = Ush + su4 * SLAB;
            float* Uw2 = Ush + su5 * SLAB;
            float* Dw1 = Dsh + sd3 * SLAB;
            float* Dw2 = Dsh + sd4 * SLAB;
            Uw1[tid] = sua0; Uw1[tid + NTHR] = sua1; if (a2) Uw1[tid + 2 * NTHR] = sua2;
            Uw2[tid] = sub0; Uw2[tid + NTHR] = sub1; if (a2) Uw2[tid + 2 * NTHR] = sub2;
            Dw1[tid] = sda0; Dw1[tid + NTHR] = sda1; if (a2) Dw1[tid + 2 * NTHR] = sda2;
            Dw2[tid] = sdb0; Dw2[tid + NTHR] = sdb1; if (a2) Dw2[tid + 2 * NTHR] = sdb2;
            __syncthreads();
            int t0 = su0, t1 = su1;
            su0 = su2; su1 = su3; su2 = su4; su3 = su5; su4 = t0; su5 = t1;
            t0 = sd0;
            sd0 = sd2; sd2 = sd4; sd4 = sd1; sd1 = sd3; sd3 = t0;
            rA = rnA; rB = rnB;
        }
    }
}

extern "C" void kernel_launch(void* const* d_in, const int* in_sizes, int n_in,
                              void* d_out, int out_size, void* d_ws, size_t ws_size,
                              hipStream_t stream) {
    const float* u   = (const float*)d_in[0];
    const float* Dd  = (const float*)d_in[1];
    const float* rho = (const float*)d_in[2];
    float* out = (float*)d_out;

    dim3 block(32, 16, 1);                     // 512 threads
    const int grid = 3 * 12 * 8 * 4;           // xt*yt*zc*b = 1152
    fk_kernel<<<grid, block, 0, stream>>>(u, Dd, rho, out);
}

// Round 11
// 112.217 us; speedup vs baseline: 1.3986x; 1.0698x over previous
//
#include <hip/hip_runtime.h>

// Fisher-Kolmogorov PDE: out = div(D * grad(u)) + rho * u * (1 - u)
// Per-axis reference semantics (replicate padding on u, then on flux):
//   div[c] = 0.25 * (f(min(c+1,n-1)) - f(max(c-1,0))),
//   f(j)   = D[j] * (u[min(j+1,n-1)] - u[max(j-1,0)])
// Shape: [B=4, C=1, 192^3], float32.
//
// R7 structure: register-past / LDS-future z-march, free-slab staging, ONE
// barrier per plane. Rings: u {z,z+1,z+2,free} 4 slabs, D {z,z+1,free} 3
// slabs, slab [20][68] floats -> 38.1 KB -> 4 blocks/CU.
// New this round:
//  (1) XCD-bijective swizzle (1152 = 8*144): each XCD gets 96 contiguous
//      z-planes of one batch -> halo + cross-replay reuse stays in its own
//      L2/L3 slice (R4 measured FETCH 386->167 MB with this mapping).
//  (2) float2 staging via pair map (edge pairs both-clamp -> broadcast):
//      halves staging VMEM + ds_write instruction counts.
//  (3) nontemporal out-store and rho-load (zero-reuse streams; keep L2 for
//      the u/D halos).

#define NX    192
#define SP    (NX * NX)
#define ZC    24
#define LROW  68
#define SROW  20
#define SLAB  (SROW * LROW)           // 1360 floats
#define NTHR  512
#define NPAIR (SLAB / 2)              // 680
#define GRID  1152

typedef float v2f __attribute__((ext_vector_type(2)));

#define LD2(p, o) (*(const float2*)((p) + (o)))

__global__ __launch_bounds__(NTHR, 8)
void fk_kernel(const float* __restrict__ u,
               const float* __restrict__ Dd,
               const float* __restrict__ rho,
               float* __restrict__ out)
{
    __shared__ float Ush[4 * SLAB];
    __shared__ float Dsh[3 * SLAB];

    const int tx  = threadIdx.x;              // 0..31
    const int ty  = threadIdx.y;              // 0..15
    const int tid = ty * 32 + tx;             // 0..511

    // ---- XCD-bijective swizzle: hw block k runs on XCD k%8; give XCD j the
    //      contiguous logical chunk [j*144, (j+1)*144)  (1152 % 8 == 0).
    const int hw = blockIdx.x;
    int bid = (hw & 7) * (GRID / 8) + (hw >> 3);
    const int xt = bid % 3;  bid /= 3;
    const int yt = bid % 12; bid /= 12;
    const int zc = bid % 8;  bid /= 8;
    const int b  = bid;                       // 0..3

    const int x0 = xt * 64, y0 = yt * 16, z0 = zc * ZC;

    const size_t vol = (size_t)b * NX * SP;
    const float* ub = u   + vol;
    const float* db = Dd  + vol;
    const float* rb = rho + vol;
    float*       ob = out + vol;

    // ---- pair staging map: pair p -> slab row r = p/34, pair-col pc = p%34;
    //      covers gx = x0 + 2*pc - 2 .. +1, gy = y0 + r - 2 (clamped).
    //      Edge pairs (gx0 = -2 or 192) clamp both elements to one index.
    int o0, o1; bool e0, e1;
    const bool act1 = (tid < NPAIR - NTHR);   // tid < 168
    {
        const int p0 = tid;
        const int r0 = p0 / (LROW / 2), pc0 = p0 % (LROW / 2);
        int gy = y0 + r0 - 2; gy = gy < 0 ? 0 : (gy > NX - 1 ? NX - 1 : gy);
        const int gx0 = x0 + 2 * pc0 - 2;
        e0 = (gx0 < 0) || (gx0 > NX - 2);
        o0 = gy * NX + (e0 ? ((gx0 < 0) ? 0 : NX - 1) : gx0);

        const int p1 = act1 ? (NTHR + tid) : 0;
        const int r1 = p1 / (LROW / 2), pc1 = p1 % (LROW / 2);
        int gy1 = y0 + r1 - 2; gy1 = gy1 < 0 ? 0 : (gy1 > NX - 1 ? NX - 1 : gy1);
        const int gx1 = x0 + 2 * pc1 - 2;
        e1 = (gx1 < 0) || (gx1 > NX - 2);
        o1 = gy1 * NX + (e1 ? ((gx1 < 0) ? 0 : NX - 1) : gx1);
    }

    auto stage = [&](const float* pl, float2& s0, float2& s1) {
        if (!e0) s0 = *(const float2*)(pl + o0);
        else { const float f = pl[o0]; s0 = make_float2(f, f); }
        if (act1) {
            if (!e1) s1 = *(const float2*)(pl + o1);
            else { const float f = pl[o1]; s1 = make_float2(f, f); }
        }
    };
    auto wr = [&](float* slab, const float2 s0, const float2 s1) {
        *(float2*)(slab + 2 * tid) = s0;
        if (act1) *(float2*)(slab + 2 * (NTHR + tid)) = s1;
    };

    // ---- ring init: u slabs 0..2 = planes z0..z0+2, D slabs 0..1 = z0..z0+1
    {
        float2 s0, s1;
        #pragma unroll
        for (int s = 0; s < 3; ++s) {
            stage(ub + (size_t)(z0 + s) * SP, s0, s1);
            wr(Ush + s * SLAB, s0, s1);
        }
        #pragma unroll
        for (int s = 0; s < 2; ++s) {
            stage(db + (size_t)(z0 + s) * SP, s0, s1);
            wr(Dsh + s * SLAB, s0, s1);
        }
    }

    const int x  = x0 + 2 * tx;               // voxels x, x+1
    const int y  = y0 + ty;
    const int bl = (ty + 2) * LROW + (2 * tx + 2);
    const size_t gcen = (size_t)y * NX + x;

    const bool fx0 = (x == 0);
    const bool fx1 = (x + 1 == NX - 1);
    const bool fy0 = (y == 0);
    const bool fy1 = (y == NX - 1);

    // ---- per-thread register z-history (center column, clamped at z0 edge)
    const int zm1 = (z0 - 1 > 0) ? z0 - 1 : 0;
    const int zm2 = (z0 - 2 > 0) ? z0 - 2 : 0;
    float2 um1 = *(const float2*)(ub + (size_t)zm1 * SP + gcen);
    float2 um2 = *(const float2*)(ub + (size_t)zm2 * SP + gcen);
    float2 dm1 = *(const float2*)(db + (size_t)zm1 * SP + gcen);
    float2 rcur;
    {
        const v2f t = __builtin_nontemporal_load((const v2f*)(rb + (size_t)z0 * SP + gcen));
        rcur = make_float2(t.x, t.y);
    }

    __syncthreads();

    int su0 = 0, su1 = 1, su2 = 2, su3 = 3;   // planes z, z+1, z+2, free
    int sd0 = 0, sd1 = 1, sd2 = 2;            // planes z, z+1, free

    for (int iz = 0; iz < ZC; ++iz) {
        const int z  = z0 + iz;
        const bool pf = (iz + 1 < ZC);        // block-uniform

        // ---- issue staging loads (written to free slabs at step bottom) ----
        float2 uS0, uS1, dS0, dS1, rnx;
        if (pf) {
            const int zu = (z + 3 > NX - 1) ? NX - 1 : z + 3;
            const int zd = (z + 2 > NX - 1) ? NX - 1 : z + 2;
            stage(ub + (size_t)zu * SP, uS0, uS1);
            stage(db + (size_t)zd * SP, dS0, dS1);
            const v2f t = __builtin_nontemporal_load((const v2f*)(rb + (size_t)(z + 1) * SP + gcen));
            rnx = make_float2(t.x, t.y);
        }

        // ---- taps: x/y from LDS, z-past from registers, z-future from ring ----
        const float* Uc = Ush + su0 * SLAB;
        const float* Dc = Dsh + sd0 * SLAB;
        const float2 uc   = LD2(Uc, bl);
        const float2 uxm  = LD2(Uc, bl - 2);
        const float2 uxp  = LD2(Uc, bl + 2);
        const float2 uym  = LD2(Uc, bl - 2 * LROW);
        const float2 uyp  = LD2(Uc, bl + 2 * LROW);
        const float2 dc   = LD2(Dc, bl);
        const float2 dxm  = LD2(Dc, bl - 2);
        const float2 dxp  = LD2(Dc, bl + 2);
        const float2 dym  = LD2(Dc, bl - LROW);
        const float2 dyp  = LD2(Dc, bl + LROW);
        const float2 uzp2 = LD2(Ush + su2 * SLAB, bl);   // u[clamp(z+2)]
        const float2 dzp  = LD2(Dsh + sd1 * SLAB, bl);   // D[clamp(z+1)]

        // ---- x axis ----
        float divx_x = dc.y  * (uxp.x - uc.x) - dxm.y * (uc.x - uxm.x);
        float divx_y = dxp.x * (uxp.y - uc.y) - dc.x  * (uc.y - uxm.y);
        if (fx0) divx_x = dc.y * (uxp.x - uc.x) - dc.x * (uc.y - uc.x);
        if (fx1) divx_y = dc.y * (uc.y - uc.x)  - dc.x * (uc.y - uxm.y);

        // ---- y axis ----
        float divy_x = dyp.x * (uyp.x - uc.x) - dym.x * (uc.x - uym.x);
        float divy_y = dyp.y * (uyp.y - uc.y) - dym.y * (uc.y - uym.y);
        if (fy0) {
            const float2 uyp1 = LD2(Uc, bl + LROW);
            divy_x = dyp.x * (uyp.x - uc.x) - dym.x * (uyp1.x - uc.x);
            divy_y = dyp.y * (uyp.y - uc.y) - dym.y * (uyp1.y - uc.y);
        }
        if (fy1) {
            const float2 uym1 = LD2(Uc, bl - LROW);
            divy_x = dyp.x * (uc.x - uym1.x) - dym.x * (uc.x - uym.x);
            divy_y = dyp.y * (uc.y - uym1.y) - dym.y * (uc.y - uym.y);
        }

        // ---- z axis (block-uniform edge branches; past from registers) ----
        float divz_x = dzp.x * (uzp2.x - uc.x) - dm1.x * (uc.x - um2.x);
        float divz_y = dzp.y * (uzp2.y - uc.y) - dm1.y * (uc.y - um2.y);
        if (z == 0) {
            const float2 uzp1 = LD2(Ush + su1 * SLAB, bl);
            divz_x = dzp.x * (uzp2.x - uc.x) - dm1.x * (uzp1.x - uc.x);
            divz_y = dzp.y * (uzp2.y - uc.y) - dm1.y * (uzp1.y - uc.y);
        }
        if (z == NX - 1) {
            divz_x = dzp.x * (uc.x - um1.x) - dm1.x * (uc.x - um2.x);
            divz_y = dzp.y * (uc.y - um1.y) - dm1.y * (uc.y - um2.y);
        }

        // ---- reaction + nontemporal store ----
        v2f o;
        o.x = 0.25f * (divx_x + divy_x + divz_x) + rcur.x * uc.x * (1.0f - uc.x);
        o.y = 0.25f * (divx_y + divy_y + divz_y) + rcur.y * uc.y * (1.0f - uc.y);
        __builtin_nontemporal_store(o, (v2f*)(ob + (size_t)z * SP + gcen));

        // ---- roll register history ----
        um2 = um1; um1 = uc; dm1 = dc;

        // ---- write staged planes into FREE slabs, ONE barrier, rotate ----
        if (pf) {
            wr(Ush + su3 * SLAB, uS0, uS1);
            wr(Dsh + sd2 * SLAB, dS0, dS1);
            __syncthreads();
            int t = su0; su0 = su1; su1 = su2; su2 = su3; su3 = t;
            t = sd0; sd0 = sd1; sd1 = sd2; sd2 = t;
            rcur = rnx;
        }
    }
}

extern "C" void kernel_launch(void* const* d_in, const int* in_sizes, int n_in,
                              void* d_out, int out_size, void* d_ws, size_t ws_size,
                              hipStream_t stream) {
    const float* u   = (const float*)d_in[0];
    const float* Dd  = (const float*)d_in[1];
    const float* rho = (const float*)d_in[2];
    float* out = (float*)d_out;

    dim3 block(32, 16, 1);                     // 512 threads
    fk_kernel<<<GRID, block, 0, stream>>>(u, Dd, rho, out);
}

// Round 12
// 110.685 us; speedup vs baseline: 1.4180x; 1.0138x over previous
//
#include <hip/hip_runtime.h>

// Fisher-Kolmogorov PDE: out = div(D * grad(u)) + rho * u * (1 - u)
// Per-axis reference semantics (replicate padding on u, then on flux):
//   div[c] = 0.25 * (f(min(c+1,n-1)) - f(max(c-1,0))),
//   f(j)   = D[j] * (u[min(j+1,n-1)] - u[max(j-1,0)])
// Shape: [B=4, C=1, 192^3], float32.
//
// R8's DISTANCE-2 staging pipeline on R7's MINIMAL ring (the two best rounds
// combined): at step z, register set B receives loads for u[z+4]/D[z+3]
// (consumed at step z+1 -> one full step of latency cover) while set A
// (loaded last step) is ds_written into the single free slab of each ring.
// Rings: u {z, z+1, z+2, free} = 4 slabs, D {z, z+1, free} = 3 slabs,
// slab [20][68] floats -> 38.1 KB -> 4 blocks/CU (R8 carried 2 free slabs
// per ring = 48 KB = 3 blocks/CU for nothing; R7 proved 74% occupancy here).
// ONE __syncthreads per plane. Register-past for z-history.

#define NX   192
#define SP   (NX * NX)
#define ZC   24
#define LROW 68
#define SROW 20
#define SLAB (SROW * LROW)            // 1360 floats
#define NTHR 512

#define LD2(p, o) (*(const float2*)((p) + (o)))

struct Stage { float u0, u1, u2, d0, d1, d2; };

__global__ __launch_bounds__(NTHR, 8)
void fk_kernel(const float* __restrict__ u,
               const float* __restrict__ Dd,
               const float* __restrict__ rho,
               float* __restrict__ out)
{
    __shared__ float Ush[4 * SLAB];
    __shared__ float Dsh[3 * SLAB];

    const int tx  = threadIdx.x;              // 0..31
    const int ty  = threadIdx.y;              // 0..15
    const int tid = ty * 32 + tx;             // 0..511

    int bid = blockIdx.x;
    const int xt = bid % 3;  bid /= 3;
    const int yt = bid % 12; bid /= 12;
    const int zc = bid % 8;  bid /= 8;
    const int b  = bid;                       // 0..3

    const int x0 = xt * 64, y0 = yt * 16, z0 = zc * ZC;

    const size_t vol = (size_t)b * NX * SP;
    const float* ub = u   + vol;
    const float* db = Dd  + vol;
    const float* rb = rho + vol;
    float*       ob = out + vol;

    // staging map: slab flat position -> clamped global (y,x) plane offset
    int g0, g1, g2;
    {
        #pragma unroll
        for (int k = 0; k < 3; ++k) {
            const int p  = tid + NTHR * k;
            const int pp = (p < SLAB) ? p : 0;
            const int r = pp / LROW, c = pp % LROW;
            int gy = y0 + r - 2; gy = gy < 0 ? 0 : (gy > NX - 1 ? NX - 1 : gy);
            int gx = x0 + c - 2; gx = gx < 0 ? 0 : (gx > NX - 1 ? NX - 1 : gx);
            const int go = gy * NX + gx;
            if (k == 0) g0 = go; else if (k == 1) g1 = go; else g2 = go;
        }
    }
    const bool a2 = (tid < SLAB - 2 * NTHR);  // tid < 336

    // ---- ring init: u slabs 0..2 = planes z0..z0+2, D slabs 0..1 = z0..z0+1
    #pragma unroll
    for (int s = 0; s < 3; ++s) {
        const float* src = ub + (size_t)(z0 + s) * SP;
        Ush[s * SLAB + tid]        = src[g0];
        Ush[s * SLAB + tid + NTHR] = src[g1];
        if (a2) Ush[s * SLAB + tid + 2 * NTHR] = src[g2];
    }
    #pragma unroll
    for (int s = 0; s < 2; ++s) {
        const float* src = db + (size_t)(z0 + s) * SP;
        Dsh[s * SLAB + tid]        = src[g0];
        Dsh[s * SLAB + tid + NTHR] = src[g1];
        if (a2) Dsh[s * SLAB + tid + 2 * NTHR] = src[g2];
    }

    const int x  = x0 + 2 * tx;               // voxels x, x+1
    const int y  = y0 + ty;
    const int bl = (ty + 2) * LROW + (2 * tx + 2);
    const size_t gcen = (size_t)y * NX + x;

    const bool fx0 = (x == 0);
    const bool fx1 = (x + 1 == NX - 1);
    const bool fy0 = (y == 0);
    const bool fy1 = (y == NX - 1);

    // ---- per-thread register z-history (center column, clamped at z0 edge)
    const int zm1 = (z0 - 1 > 0) ? z0 - 1 : 0;
    const int zm2 = (z0 - 2 > 0) ? z0 - 2 : 0;
    float2 um1 = *(const float2*)(ub + (size_t)zm1 * SP + gcen);
    float2 um2 = *(const float2*)(ub + (size_t)zm2 * SP + gcen);
    float2 dm1 = *(const float2*)(db + (size_t)zm1 * SP + gcen);
    float2 rcur = *(const float2*)(rb + (size_t)z0 * SP + gcen);

    // ---- prologue staging set A: u[z0+3], D[z0+2] ----
    Stage A, B;
    {
        const int zu = (z0 + 3 > NX - 1) ? NX - 1 : z0 + 3;
        const int zd = (z0 + 2 > NX - 1) ? NX - 1 : z0 + 2;
        const float* us = ub + (size_t)zu * SP;
        const float* ds = db + (size_t)zd * SP;
        A.u0 = us[g0]; A.u1 = us[g1]; A.u2 = a2 ? us[g2] : 0.0f;
        A.d0 = ds[g0]; A.d1 = ds[g1]; A.d2 = a2 ? ds[g2] : 0.0f;
    }

    __syncthreads();

    int su0 = 0, su1 = 1, su2 = 2, su3 = 3;   // planes z, z+1, z+2, free
    int sd0 = 0, sd1 = 1, sd2 = 2;            // planes z, z+1, free

    for (int iz = 0; iz < ZC; ++iz) {
        const int z  = z0 + iz;
        const bool wrA    = (iz + 1 < ZC);    // block-uniform
        const bool issueB = (iz + 2 < ZC);

        // ---- issue NEXT-next staging loads into B (consumed at step z+1) ----
        float2 rnx;
        if (issueB) {
            const int zu = (z + 4 > NX - 1) ? NX - 1 : z + 4;
            const int zd = (z + 3 > NX - 1) ? NX - 1 : z + 3;
            const float* us = ub + (size_t)zu * SP;
            const float* ds = db + (size_t)zd * SP;
            B.u0 = us[g0]; B.u1 = us[g1]; if (a2) B.u2 = us[g2];
            B.d0 = ds[g0]; B.d1 = ds[g1]; if (a2) B.d2 = ds[g2];
        }
        if (wrA) rnx = *(const float2*)(rb + (size_t)(z + 1) * SP + gcen);

        // ---- taps: x/y from LDS, z-past from registers, z-future from ring ----
        const float* Uc = Ush + su0 * SLAB;
        const float* Dc = Dsh + sd0 * SLAB;
        const float2 uc   = LD2(Uc, bl);
        const float2 uxm  = LD2(Uc, bl - 2);
        const float2 uxp  = LD2(Uc, bl + 2);
        const float2 uym  = LD2(Uc, bl - 2 * LROW);
        const float2 uyp  = LD2(Uc, bl + 2 * LROW);
        const float2 dc   = LD2(Dc, bl);
        const float2 dxm  = LD2(Dc, bl - 2);
        const float2 dxp  = LD2(Dc, bl + 2);
        const float2 dym  = LD2(Dc, bl - LROW);
        const float2 dyp  = LD2(Dc, bl + LROW);
        const float2 uzp2 = LD2(Ush + su2 * SLAB, bl);   // u[clamp(z+2)]
        const float2 dzp  = LD2(Dsh + sd1 * SLAB, bl);   // D[clamp(z+1)]

        // ---- x axis ----
        float divx_x = dc.y  * (uxp.x - uc.x) - dxm.y * (uc.x - uxm.x);
        float divx_y = dxp.x * (uxp.y - uc.y) - dc.x  * (uc.y - uxm.y);
        if (fx0) divx_x = dc.y * (uxp.x - uc.x) - dc.x * (uc.y - uc.x);
        if (fx1) divx_y = dc.y * (uc.y - uc.x)  - dc.x * (uc.y - uxm.y);

        // ---- y axis ----
        float divy_x = dyp.x * (uyp.x - uc.x) - dym.x * (uc.x - uym.x);
        float divy_y = dyp.y * (uyp.y - uc.y) - dym.y * (uc.y - uym.y);
        if (fy0) {
            const float2 uyp1 = LD2(Uc, bl + LROW);
            divy_x = dyp.x * (uyp.x - uc.x) - dym.x * (uyp1.x - uc.x);
            divy_y = dyp.y * (uyp.y - uc.y) - dym.y * (uyp1.y - uc.y);
        }
        if (fy1) {
            const float2 uym1 = LD2(Uc, bl - LROW);
            divy_x = dyp.x * (uc.x - uym1.x) - dym.x * (uc.x - uym.x);
            divy_y = dyp.y * (uc.y - uym1.y) - dym.y * (uc.y - uym.y);
        }

        // ---- z axis (block-uniform edge branches; past from registers) ----
        float divz_x = dzp.x * (uzp2.x - uc.x) - dm1.x * (uc.x - um2.x);
        float divz_y = dzp.y * (uzp2.y - uc.y) - dm1.y * (uc.y - um2.y);
        if (z == 0) {
            const float2 uzp1 = LD2(Ush + su1 * SLAB, bl);
            divz_x = dzp.x * (uzp2.x - uc.x) - dm1.x * (uzp1.x - uc.x);
            divz_y = dzp.y * (uzp2.y - uc.y) - dm1.y * (uzp1.y - uc.y);
        }
        if (z == NX - 1) {
            divz_x = dzp.x * (uc.x - um1.x) - dm1.x * (uc.x - um2.x);
            divz_y = dzp.y * (uc.y - um1.y) - dm1.y * (uc.y - um2.y);
        }

        // ---- reaction + store ----
        float2 o;
        o.x = 0.25f * (divx_x + divy_x + divz_x) + rcur.x * uc.x * (1.0f - uc.x);
        o.y = 0.25f * (divx_y + divy_y + divz_y) + rcur.y * uc.y * (1.0f - uc.y);
        *(float2*)(ob + (size_t)z * SP + gcen) = o;

        // ---- roll register history ----
        um2 = um1; um1 = uc; dm1 = dc;

        // ---- write set A (loads 1 full step old) into free slabs, rotate ----
        if (wrA) {
            float* Uw = Ush + su3 * SLAB;
            float* Dw = Dsh + sd2 * SLAB;
            Uw[tid] = A.u0; Uw[tid + NTHR] = A.u1; if (a2) Uw[tid + 2 * NTHR] = A.u2;
            Dw[tid] = A.d0; Dw[tid + NTHR] = A.d1; if (a2) Dw[tid + 2 * NTHR] = A.d2;
            __syncthreads();
            int t = su0; su0 = su1; su1 = su2; su2 = su3; su3 = t;
            t = sd0; sd0 = sd1; sd1 = sd2; sd2 = t;
            A = B;
            rcur = rnx;
        }
    }
}

extern "C" void kernel_launch(void* const* d_in, const int* in_sizes, int n_in,
                              void* d_out, int out_size, void* d_ws, size_t ws_size,
                              hipStream_t stream) {
    const float* u   = (const float*)d_in[0];
    const float* Dd  = (const float*)d_in[1];
    const float* rho = (const float*)d_in[2];
    float* out = (float*)d_out;

    dim3 block(32, 16, 1);                     // 512 threads
    const int grid = 3 * 12 * 8 * 4;           // xt*yt*zc*b = 1152
    fk_kernel<<<grid, block, 0, stream>>>(u, Dd, rho, out);
}

// Round 13
// 107.988 us; speedup vs baseline: 1.4534x; 1.0250x over previous
//
#include <hip/hip_runtime.h>

// Fisher-Kolmogorov PDE: out = div(D * grad(u)) + rho * u * (1 - u)
// Per-axis reference semantics (replicate padding on u, then on flux):
//   div[c] = 0.25 * (f(min(c+1,n-1)) - f(max(c-1,0))),
//   f(j)   = D[j] * (u[min(j+1,n-1)] - u[max(j-1,0)])
// Shape: [B=4, C=1, 192^3], float32.
//
// FINAL (measured best, R8 = 108.2 us): register-past / LDS-future z-march
// with a DISTANCE-2 staging pipeline: at step z, register set B receives
// loads for u[z+4]/D[z+3] while set A (loaded at step z-1, ~2400 cyc ago ->
// HBM latency fully covered) is ds_written into the free slabs. Rings:
// u {z,z+1,z+2,F1,F2} = 5 slabs, D {z,z+1,G1,G2} = 4 slabs; 47.8 KB total.
// ONE __syncthreads per plane. Block (32,16), tile 64x16, ZC=24, 1152 blocks.
//
// Session summary (12 rounds): naive row/thread 126us -> LDS z-march 110.8
// (R5) -> +reg-past/1-barrier (R7, 110.7) -> +distance-2 staging (R8, 108.2).
// Falsified binders: HBM BW (38% used; cutting FETCH 300->167/245 MB didn't
// help), VMEM issue rate (4x fewer instrs was slower), occupancy 56->74%
// (no delta), barrier count 24->12 (slower via LDS growth), L2/XCD locality
// (swizzle neutral), NT hints (neutral). Remaining time = additive per-step
// latency chain (ds_read ~120cy + VALU tree + staging + barrier) x 24 steps
// at ~3 blocks/CU -- no pipe saturated; latency-bound floor ~108 us.

#define NX   192
#define SP   (NX * NX)
#define ZC   24
#define LROW 68
#define SROW 20
#define SLAB (SROW * LROW)            // 1360 floats
#define NTHR 512

#define LD2(p, o) (*(const float2*)((p) + (o)))

struct Stage { float u0, u1, u2, d0, d1, d2; };

__global__ __launch_bounds__(NTHR, 6)
void fk_kernel(const float* __restrict__ u,
               const float* __restrict__ Dd,
               const float* __restrict__ rho,
               float* __restrict__ out)
{
    __shared__ float Ush[5 * SLAB];
    __shared__ float Dsh[4 * SLAB];

    const int tx  = threadIdx.x;              // 0..31
    const int ty  = threadIdx.y;              // 0..15
    const int tid = ty * 32 + tx;             // 0..511

    int bid = blockIdx.x;
    const int xt = bid % 3;  bid /= 3;
    const int yt = bid % 12; bid /= 12;
    const int zc = bid % 8;  bid /= 8;
    const int b  = bid;                       // 0..3

    const int x0 = xt * 64, y0 = yt * 16, z0 = zc * ZC;

    const size_t vol = (size_t)b * NX * SP;
    const float* ub = u   + vol;
    const float* db = Dd  + vol;
    const float* rb = rho + vol;
    float*       ob = out + vol;

    // staging map: slab flat position -> clamped global (y,x) plane offset
    int g0, g1, g2;
    {
        #pragma unroll
        for (int k = 0; k < 3; ++k) {
            const int p  = tid + NTHR * k;
            const int pp = (p < SLAB) ? p : 0;
            const int r = pp / LROW, c = pp % LROW;
            int gy = y0 + r - 2; gy = gy < 0 ? 0 : (gy > NX - 1 ? NX - 1 : gy);
            int gx = x0 + c - 2; gx = gx < 0 ? 0 : (gx > NX - 1 ? NX - 1 : gx);
            const int go = gy * NX + gx;
            if (k == 0) g0 = go; else if (k == 1) g1 = go; else g2 = go;
        }
    }
    const bool a2 = (tid < SLAB - 2 * NTHR);  // tid < 336

    // ---- ring init: u slabs 0..2 = planes z0..z0+2, D slabs 0..1 = z0..z0+1
    #pragma unroll
    for (int s = 0; s < 3; ++s) {
        const float* src = ub + (size_t)(z0 + s) * SP;
        Ush[s * SLAB + tid]        = src[g0];
        Ush[s * SLAB + tid + NTHR] = src[g1];
        if (a2) Ush[s * SLAB + tid + 2 * NTHR] = src[g2];
    }
    #pragma unroll
    for (int s = 0; s < 2; ++s) {
        const float* src = db + (size_t)(z0 + s) * SP;
        Dsh[s * SLAB + tid]        = src[g0];
        Dsh[s * SLAB + tid + NTHR] = src[g1];
        if (a2) Dsh[s * SLAB + tid + 2 * NTHR] = src[g2];
    }

    const int x  = x0 + 2 * tx;               // voxels x, x+1
    const int y  = y0 + ty;
    const int bl = (ty + 2) * LROW + (2 * tx + 2);
    const size_t gcen = (size_t)y * NX + x;

    const bool fx0 = (x == 0);
    const bool fx1 = (x + 1 == NX - 1);
    const bool fy0 = (y == 0);
    const bool fy1 = (y == NX - 1);

    // ---- per-thread register z-history (center column, clamped at z0 edge) ----
    const int zm1 = (z0 - 1 > 0) ? z0 - 1 : 0;
    const int zm2 = (z0 - 2 > 0) ? z0 - 2 : 0;
    float2 um1 = *(const float2*)(ub + (size_t)zm1 * SP + gcen);
    float2 um2 = *(const float2*)(ub + (size_t)zm2 * SP + gcen);
    float2 dm1 = *(const float2*)(db + (size_t)zm1 * SP + gcen);
    float2 rcur = *(const float2*)(rb + (size_t)z0 * SP + gcen);

    // ---- prologue staging set A: u[z0+3], D[z0+2] ----
    Stage A, B;
    {
        const int zu = (z0 + 3 > NX - 1) ? NX - 1 : z0 + 3;
        const int zd = (z0 + 2 > NX - 1) ? NX - 1 : z0 + 2;
        const float* us = ub + (size_t)zu * SP;
        const float* ds = db + (size_t)zd * SP;
        A.u0 = us[g0]; A.u1 = us[g1]; A.u2 = a2 ? us[g2] : 0.0f;
        A.d0 = ds[g0]; A.d1 = ds[g1]; A.d2 = a2 ? ds[g2] : 0.0f;
    }

    __syncthreads();

    int su0 = 0, su1 = 1, su2 = 2, su3 = 3, su4 = 4;  // planes z, z+1, z+2, F1, F2
    int sd0 = 0, sd1 = 1, sd2 = 2, sd3 = 3;           // planes z, z+1, G1, G2

    for (int iz = 0; iz < ZC; ++iz) {
        const int z  = z0 + iz;
        const bool wrA    = (iz + 1 < ZC);    // block-uniform
        const bool issueB = (iz + 2 < ZC);

        // ---- issue NEXT-next staging loads into B (consumed at step z+1) ----
        float2 rnx;
        if (issueB) {
            const int zu = (z + 4 > NX - 1) ? NX - 1 : z + 4;
            const int zd = (z + 3 > NX - 1) ? NX - 1 : z + 3;
            const float* us = ub + (size_t)zu * SP;
            const float* ds = db + (size_t)zd * SP;
            B.u0 = us[g0]; B.u1 = us[g1]; if (a2) B.u2 = us[g2];
            B.d0 = ds[g0]; B.d1 = ds[g1]; if (a2) B.d2 = ds[g2];
        }
        if (wrA) rnx = *(const float2*)(rb + (size_t)(z + 1) * SP + gcen);

        // ---- taps: x/y from LDS, z-past from registers, z-future from ring ----
        const float* Uc = Ush + su0 * SLAB;
        const float* Dc = Dsh + sd0 * SLAB;
        const float2 uc   = LD2(Uc, bl);
        const float2 uxm  = LD2(Uc, bl - 2);
        const float2 uxp  = LD2(Uc, bl + 2);
        const float2 uym  = LD2(Uc, bl - 2 * LROW);
        const float2 uyp  = LD2(Uc, bl + 2 * LROW);
        const float2 dc   = LD2(Dc, bl);
        const float2 dxm  = LD2(Dc, bl - 2);
        const float2 dxp  = LD2(Dc, bl + 2);
        const float2 dym  = LD2(Dc, bl - LROW);
        const float2 dyp  = LD2(Dc, bl + LROW);
        const float2 uzp2 = LD2(Ush + su2 * SLAB, bl);   // u[clamp(z+2)]
        const float2 dzp  = LD2(Dsh + sd1 * SLAB, bl);   // D[clamp(z+1)]

        // ---- x axis ----
        float divx_x = dc.y  * (uxp.x - uc.x) - dxm.y * (uc.x - uxm.x);
        float divx_y = dxp.x * (uxp.y - uc.y) - dc.x  * (uc.y - uxm.y);
        if (fx0) divx_x = dc.y * (uxp.x - uc.x) - dc.x * (uc.y - uc.x);
        if (fx1) divx_y = dc.y * (uc.y - uc.x)  - dc.x * (uc.y - uxm.y);

        // ---- y axis ----
        float divy_x = dyp.x * (uyp.x - uc.x) - dym.x * (uc.x - uym.x);
        float divy_y = dyp.y * (uyp.y - uc.y) - dym.y * (uc.y - uym.y);
        if (fy0) {
            const float2 uyp1 = LD2(Uc, bl + LROW);
            divy_x = dyp.x * (uyp.x - uc.x) - dym.x * (uyp1.x - uc.x);
            divy_y = dyp.y * (uyp.y - uc.y) - dym.y * (uyp1.y - uc.y);
        }
        if (fy1) {
            const float2 uym1 = LD2(Uc, bl - LROW);
            divy_x = dyp.x * (uc.x - uym1.x) - dym.x * (uc.x - uym.x);
            divy_y = dyp.y * (uc.y - uym1.y) - dym.y * (uc.y - uym.y);
        }

        // ---- z axis (block-uniform edge branches; past from registers) ----
        float divz_x = dzp.x * (uzp2.x - uc.x) - dm1.x * (uc.x - um2.x);
        float divz_y = dzp.y * (uzp2.y - uc.y) - dm1.y * (uc.y - um2.y);
        if (z == 0) {
            const float2 uzp1 = LD2(Ush + su1 * SLAB, bl);
            divz_x = dzp.x * (uzp2.x - uc.x) - dm1.x * (uzp1.x - uc.x);
            divz_y = dzp.y * (uzp2.y - uc.y) - dm1.y * (uzp1.y - uc.y);
        }
        if (z == NX - 1) {
            divz_x = dzp.x * (uc.x - um1.x) - dm1.x * (uc.x - um2.x);
            divz_y = dzp.y * (uc.y - um1.y) - dm1.y * (uc.y - um2.y);
        }

        // ---- reaction + store ----
        float2 o;
        o.x = 0.25f * (divx_x + divy_x + divz_x) + rcur.x * uc.x * (1.0f - uc.x);
        o.y = 0.25f * (divx_y + divy_y + divz_y) + rcur.y * uc.y * (1.0f - uc.y);
        *(float2*)(ob + (size_t)z * SP + gcen) = o;

        // ---- roll register history ----
        um2 = um1; um1 = uc; dm1 = dc;

        // ---- write set A (loads 1 full step old) into free slabs, rotate ----
        if (wrA) {
            float* Uw = Ush + su3 * SLAB;
            float* Dw = Dsh + sd2 * SLAB;
            Uw[tid] = A.u0; Uw[tid + NTHR] = A.u1; if (a2) Uw[tid + 2 * NTHR] = A.u2;
            Dw[tid] = A.d0; Dw[tid + NTHR] = A.d1; if (a2) Dw[tid + 2 * NTHR] = A.d2;
            __syncthreads();
            int t = su0; su0 = su1; su1 = su2; su2 = su3; su3 = su4; su4 = t;
            t = sd0; sd0 = sd1; sd1 = sd2; sd2 = sd3; sd3 = t;
            A = B;
            rcur = rnx;
        }
    }
}

extern "C" void kernel_launch(void* const* d_in, const int* in_sizes, int n_in,
                              void* d_out, int out_size, void* d_ws, size_t ws_size,
                              hipStream_t stream) {
    const float* u   = (const float*)d_in[0];
    const float* Dd  = (const float*)d_in[1];
    const float* rho = (const float*)d_in[2];
    float* out = (float*)d_out;

    dim3 block(32, 16, 1);                     // 512 threads
    const int grid = 3 * 12 * 8 * 4;           // xt*yt*zc*b = 1152
    fk_kernel<<<grid, block, 0, stream>>>(u, Dd, rho, out);
}